// Round 14
// baseline (365.277 us; speedup 1.0000x reference)
//
#include <hip/hip_runtime.h>
#include <hip/hip_cooperative_groups.h>
#include <math.h>

namespace cg = cooperative_groups;

#define BB   4
#define NN   4096
#define DD   128
#define NCLS 5
#define SS   800      // (N - NQ) / NCLS
#define KK   400      // int(0.5 * S)
#define NQ   96
#define MM   (NCLS*KK + NQ)   // 2096
#define NSUP (NCLS*SS)        // 4000

typedef float f4 __attribute__((ext_vector_type(4)));
typedef int   i4 __attribute__((ext_vector_type(4)));

// Single cooperative kernel: phaseA score -> grid.sync -> phaseB topk (blocks 0..19)
// -> grid.sync -> phaseC newxa. Phase bodies carry the R13-verified numerics/sort
// semantics verbatim; only the thread partitioning of the sort changed (256thr x 4key,
// mechanically identical bitonic network).
__global__ void __launch_bounds__(256, 8)
fused_kernel(const float* __restrict__ A, const float* __restrict__ X,
             const float* __restrict__ W, const float* __restrict__ bias,
             float* __restrict__ scoreF, int* __restrict__ gidx, float* __restrict__ gvals,
             float* __restrict__ outA, float* __restrict__ outX, float* __restrict__ outIdx) {
    __shared__ union {
        float rowA[NN];                      // phase C: 16 KB staged A-row
        unsigned long long sbuf[2][1024];    // phase B: double-buffered sort exchange
    } sm;
    cg::grid_group grid = cg::this_grid();
    const int wv = threadIdx.x >> 6, ln = threadIdx.x & 63;

    // ---------------- phase A: scores (R2/R3-verified numerics, verbatim) ----------------
    {
        const double Wd0 = (double)W[ln];
        const double Wd1 = (double)W[ln + 64];
        const float  b0  = bias[0];
        const int wid = blockIdx.x * 4 + wv;          // 0..8191
        #pragma unroll
        for (int r = 0; r < 2; ++r) {
            const int row = wid * 2 + r;              // 0..16383 = b*NN + n
            const float* x = X + (size_t)row * DD;
            double acc = (double)x[ln] * Wd0 + (double)x[ln + 64] * Wd1;
            #pragma unroll
            for (int off = 32; off > 0; off >>= 1) acc += __shfl_down(acc, off);
            if (ln == 0) {
                float z32 = (float)acc;
                float u   = (z32 + b0) / 100.0f;
                float e   = (float)exp(-(double)u);
                scoreF[row] = 1.0f / (1.0f + e);
            }
        }
    }
    grid.sync();

    // ---------------- phase B: top-400 per (b,class), blocks 0..19 ----------------
    if (blockIdx.x < BB * NCLS) {
        const int b = blockIdx.x / NCLS;
        const int c = blockIdx.x % NCLS;
        const int t = threadIdx.x;

        if (c == 0 && t < NQ) {                       // queries (independent of sort)
            gidx [b * MM + NCLS * KK + t] = NSUP + t;
            gvals[b * MM + NCLS * KK + t] = scoreF[(size_t)b * NN + NSUP + t];
        }

        // keys: (f32 score bits << 32) | (1023 - e); thread t holds elems e = t + 256r
        const float* sc = scoreF + (size_t)b * NN + c * SS;
        unsigned long long v[4];
        #pragma unroll
        for (int r = 0; r < 4; ++r) {
            int e = t + 256 * r;
            v[r] = (e < SS)
                 ? (((unsigned long long)__float_as_uint(sc[e]) << 32) | (unsigned int)(1023 - e))
                 : 0ull;                               // pad sinks
        }

        int p = 0;
        for (int k = 2; k <= 1024; k <<= 1) {
            for (int j = k >> 1; j > 0; j >>= 1) {
                if (j >= 256) {
                    // same-thread register pairs (r, r^(j>>8)); elem e1&k == e0&k here,
                    // so elem e0 keeps max iff ((e0&k)==0), e1 the complement.
                    const int rj = j >> 8;             // 1 or 2
                    #pragma unroll
                    for (int r = 0; r < 4; ++r) {
                        if ((r & rj) == 0) {
                            const int r2 = r | rj;
                            const int e0 = t + 256 * r;
                            const bool desc = ((e0 & k) == 0);
                            unsigned long long hi = v[r] > v[r2] ? v[r] : v[r2];
                            unsigned long long lo = v[r] > v[r2] ? v[r2] : v[r];
                            v[r]  = desc ? hi : lo;
                            v[r2] = desc ? lo : hi;
                        }
                    }
                } else if (j >= 64) {
                    // cross-wave exchange via double-buffered LDS (j = 64 or 128)
                    #pragma unroll
                    for (int r = 0; r < 4; ++r) sm.sbuf[p][t + 256 * r] = v[r];
                    __syncthreads();
                    #pragma unroll
                    for (int r = 0; r < 4; ++r) {
                        unsigned long long o = sm.sbuf[p][(t ^ j) + 256 * r];
                        const int e = t + 256 * r;
                        const bool keepMax = (((e & k) == 0) == ((t & j) == 0));
                        v[r] = keepMax ? (v[r] > o ? v[r] : o) : (v[r] < o ? v[r] : o);
                    }
                    p ^= 1;   // next write targets the other half (reads of this half are
                              // separated from its next write by the next stage's barrier)
                } else {
                    // intra-wave exchange via shfl_xor (e&j == t&j for j<64)
                    #pragma unroll
                    for (int r = 0; r < 4; ++r) {
                        unsigned int lo32 = __shfl_xor((unsigned int)(v[r] & 0xFFFFFFFFu), j);
                        unsigned int hi32 = __shfl_xor((unsigned int)(v[r] >> 32), j);
                        unsigned long long o = ((unsigned long long)hi32 << 32) | lo32;
                        const int e = t + 256 * r;
                        const bool keepMax = (((e & k) == 0) == ((t & j) == 0));
                        v[r] = keepMax ? (v[r] > o ? v[r] : o) : (v[r] < o ? v[r] : o);
                    }
                }
            }
        }

        // emit top-KK (elems 0..399 hold the descending top-400)
        #pragma unroll
        for (int r = 0; r < 2; ++r) {
            const int e = t + 256 * r;
            if (e < KK) {
                const int li = 1023 - (int)(v[r] & 0xFFFFFFFFull);
                gidx [b * MM + c * KK + e] = c * SS + li;
                gvals[b * MM + c * KK + e] = __uint_as_float((unsigned int)(v[r] >> 32));
            }
        }
    }
    grid.sync();

    // ---------------- phase C: newxa (R13-verified body, grid-stride) ----------------
    for (int bm = blockIdx.x; bm < BB * MM; bm += gridDim.x) {
        const int b  = bm / MM;
        const int ri = gidx[bm];              // broadcast scalar load (L2-hot)

        // async stage of the 16KB A row (4 global_load_lds_dwordx4 / wave)
        {
            const float* arow = A + ((size_t)b * NN + ri) * NN;
            #pragma unroll
            for (int sgm = 0; sgm < 4; ++sgm) {
                int base = (wv * 4 + sgm) * 256;               // float offset, wave-uniform
                const float* gsrc = arow + base + ln * 4;      // per-lane global addr
                float*       ldst = sm.rowA + base;            // wave-uniform LDS base
                __builtin_amdgcn_global_load_lds(
                    (__attribute__((address_space(1))) void*)(const_cast<float*>(gsrc)),
                    (__attribute__((address_space(3))) void*)(ldst),
                    16, 0, 0);
            }
        }

        // newX + idx overlap the staging latency
        if (threadIdx.x < DD) {
            float vscale = gvals[bm];
            float xv = X[((size_t)b * NN + ri) * DD + threadIdx.x] * vscale;
            __builtin_nontemporal_store(xv, outX + (size_t)bm * DD + threadIdx.x);
            if (threadIdx.x == 0) outIdx[bm] = (float)ri;
        }
        __syncthreads();   // drains vmcnt (global_load_lds)

        // gather: indices via int4 from L2, values from LDS, nt f4 stores
        const int* gb = gidx + b * MM;        // 16B-aligned
        float* orow = outA + (size_t)bm * MM;
        for (int jj = threadIdx.x * 4; jj < MM; jj += 1024) {
            i4 c4 = *(const i4*)(gb + jj);
            f4 vv;
            vv.x = sm.rowA[c4.x];
            vv.y = sm.rowA[c4.y];
            vv.z = sm.rowA[c4.z];
            vv.w = sm.rowA[c4.w];
            __builtin_nontemporal_store(vv, (f4*)(orow + jj));
        }
        __syncthreads();   // rowA reuse guard before next iteration's staging
    }
}

extern "C" void kernel_launch(void* const* d_in, const int* in_sizes, int n_in,
                              void* d_out, int out_size, void* d_ws, size_t ws_size,
                              hipStream_t stream) {
    const float* A  = (const float*)d_in[0];
    const float* X  = (const float*)d_in[1];
    const float* W  = (const float*)d_in[2];
    const float* bi = (const float*)d_in[3];

    float* outA   = (float*)d_out;                         // B*M*M
    float* outX   = outA + (size_t)BB * MM * MM;           // B*M*D
    float* outIdx = outX + (size_t)BB * MM * DD;           // B*M

    char* ws = (char*)d_ws;
    float* scoreF = (float*)ws;                                 // B*N*4 = 65536
    int*   gidx   = (int*)  (ws + 65536);                       // B*M*4 = 33536
    float* gvals  = (float*)(ws + 65536 + 33536);               // B*M*4 = 33536

    void* args[] = { (void*)&A, (void*)&X, (void*)&W, (void*)&bi,
                     (void*)&scoreF, (void*)&gidx, (void*)&gvals,
                     (void*)&outA, (void*)&outX, (void*)&outIdx };
    hipLaunchCooperativeKernel((const void*)fused_kernel, dim3(2048), dim3(256),
                               args, 0, stream);
}

// Round 15
// 52.568 us; speedup vs baseline: 6.9486x; 6.9486x over previous
//
#include <hip/hip_runtime.h>
#include <math.h>

#define BB   4
#define NN   4096
#define DD   128
#define NCLS 5
#define SS   800      // (N - NQ) / NCLS
#define KK   400      // int(0.5 * S)
#define NQ   96
#define MM   (NCLS*KK + NQ)   // 2096
#define NSUP (NCLS*SS)        // 4000

typedef float f4 __attribute__((ext_vector_type(4)));
typedef int   i4 __attribute__((ext_vector_type(4)));

// ---------------- scores: f64 dot, exact f32 sigmoid (R2/R3-verified, verbatim) ----------------
__global__ void score_kernel(const float* __restrict__ X, const float* __restrict__ W,
                             const float* __restrict__ bias,
                             float* __restrict__ scoreF) {
    int row  = blockIdx.x * 4 + (threadIdx.x >> 6);   // 4 waves / block
    int lane = threadIdx.x & 63;
    if (row >= BB * NN) return;
    const float* x = X + (size_t)row * DD;
    double acc = (double)x[lane]      * (double)W[lane]
               + (double)x[lane + 64] * (double)W[lane + 64];
    #pragma unroll
    for (int off = 32; off > 0; off >>= 1) acc += __shfl_down(acc, off);
    if (lane == 0) {
        float z32 = (float)acc;
        float u   = (z32 + bias[0]) / 100.0f;
        float e   = (float)exp(-(double)u);
        float t   = 1.0f + e;
        float s   = 1.0f / t;
        scoreF[row] = s;
    }
}

// ---------------- top-400 per (b,class): register bitonic (R3-verified, verbatim) ----------------
__global__ void __launch_bounds__(1024)
topk_kernel(const float* __restrict__ scoreF, int* __restrict__ gidx, float* __restrict__ gvals) {
    __shared__ unsigned long long buf[2][1024];
    const int b = blockIdx.x / NCLS;
    const int c = blockIdx.x % NCLS;
    const int t = threadIdx.x;

    if (c == 0 && t >= 512 && t < 512 + NQ) {
        int q  = t - 512;
        int gi = NSUP + q;
        int m  = NCLS * KK + q;
        gidx [b * MM + m] = gi;
        gvals[b * MM + m] = scoreF[(size_t)b * NN + gi];
    }

    const float* sc = scoreF + (size_t)b * NN + c * SS;
    unsigned long long v = 0ull;    // pad sinks
    if (t < SS)
        v = ((unsigned long long)__float_as_uint(sc[t]) << 32) | (unsigned int)(1023 - t);

    int p = 0;
    for (int k = 2; k <= 1024; k <<= 1) {
        for (int j = k >> 1; j > 0; j >>= 1) {
            unsigned long long o;
            if (j >= 64) {
                buf[p][t] = v;
                __syncthreads();
                o = buf[p][t ^ j];
                p ^= 1;   // next reuse of this buffer is 2 stages (1 barrier) away
            } else {
                unsigned int lo = __shfl_xor((unsigned int)(v & 0xFFFFFFFFu), j);
                unsigned int hi = __shfl_xor((unsigned int)(v >> 32), j);
                o = ((unsigned long long)hi << 32) | lo;
            }
            bool keepMax = (((t & k) == 0) == ((t & j) == 0));
            v = keepMax ? (v > o ? v : o) : (v < o ? v : o);
        }
    }

    if (t < KK) {
        int li = 1023 - (int)(v & 0xFFFFFFFFull);
        gidx [b * MM + c * KK + t] = c * SS + li;
        gvals[b * MM + c * KK + t] = __uint_as_float((unsigned int)(v >> 32));
    }
}

// ---------------- fused new_A + new_X + idx: persistent grid + nt stores (R13-verified) ----------------
__global__ void __launch_bounds__(256, 8)
newxa_kernel(const float* __restrict__ A, const float* __restrict__ X,
             const int* __restrict__ gidx, const float* __restrict__ gvals,
             float* __restrict__ outA, float* __restrict__ outX, float* __restrict__ outIdx) {
    __shared__ float rowA[NN];
    const int wv = threadIdx.x >> 6, ln = threadIdx.x & 63;

    for (int bm = blockIdx.x; bm < BB * MM; bm += gridDim.x) {
        const int b  = bm / MM;
        const int ri = gidx[bm];              // broadcast scalar load (L2-hot)

        // async stage of the 16KB A row (4 global_load_lds_dwordx4 / wave)
        {
            const float* arow = A + ((size_t)b * NN + ri) * NN;
            #pragma unroll
            for (int sgm = 0; sgm < 4; ++sgm) {
                int base = (wv * 4 + sgm) * 256;               // float offset, wave-uniform
                const float* gsrc = arow + base + ln * 4;      // per-lane global addr
                float*       ldst = rowA + base;               // wave-uniform LDS base
                __builtin_amdgcn_global_load_lds(
                    (__attribute__((address_space(1))) void*)(const_cast<float*>(gsrc)),
                    (__attribute__((address_space(3))) void*)(ldst),
                    16, 0, 0);
            }
        }

        // newX + idx overlap the staging latency
        if (threadIdx.x < DD) {
            float vscale = gvals[bm];
            float xv = X[((size_t)b * NN + ri) * DD + threadIdx.x] * vscale;
            __builtin_nontemporal_store(xv, outX + (size_t)bm * DD + threadIdx.x);
            if (threadIdx.x == 0) outIdx[bm] = (float)ri;
        }
        __syncthreads();   // drains vmcnt (global_load_lds)

        // gather: indices via int4 from L2, values from LDS, nt f4 stores
        const int* gb = gidx + b * MM;        // 16B-aligned
        float* orow = outA + (size_t)bm * MM;
        for (int jj = threadIdx.x * 4; jj < MM; jj += 1024) {
            i4 c4 = *(const i4*)(gb + jj);
            f4 vv;
            vv.x = rowA[c4.x];
            vv.y = rowA[c4.y];
            vv.z = rowA[c4.z];
            vv.w = rowA[c4.w];
            __builtin_nontemporal_store(vv, (f4*)(orow + jj));
        }
        __syncthreads();   // rowA reuse guard before next iteration's staging
    }
}

extern "C" void kernel_launch(void* const* d_in, const int* in_sizes, int n_in,
                              void* d_out, int out_size, void* d_ws, size_t ws_size,
                              hipStream_t stream) {
    const float* A  = (const float*)d_in[0];
    const float* X  = (const float*)d_in[1];
    const float* W  = (const float*)d_in[2];
    const float* bi = (const float*)d_in[3];

    float* outA   = (float*)d_out;                         // B*M*M
    float* outX   = outA + (size_t)BB * MM * MM;           // B*M*D
    float* outIdx = outX + (size_t)BB * MM * DD;           // B*M

    char* ws = (char*)d_ws;
    float* scoreF = (float*)ws;                                 // B*N*4 = 65536
    int*   gidx   = (int*)  (ws + 65536);                       // B*M*4 = 33536
    float* gvals  = (float*)(ws + 65536 + 33536);               // B*M*4 = 33536

    score_kernel<<<(BB * NN) / 4, 256, 0, stream>>>(X, W, bi, scoreF);
    topk_kernel<<<BB * NCLS, 1024, 0, stream>>>(scoreF, gidx, gvals);
    newxa_kernel<<<2048, 256, 0, stream>>>(A, X, gidx, gvals, outA, outX, outIdx);
}